// Round 1
// baseline (1110.153 us; speedup 1.0000x reference)
//
#include <hip/hip_runtime.h>
#include <hip/hip_bf16.h>

#define D 128
#define N0_ 1048576
#define N1_ 131072
#define N2_ 8192
#define E0_ 1048576
#define E1_ 131072

typedef float f32x4 __attribute__((ext_vector_type(4)));
typedef short bf16x8 __attribute__((ext_vector_type(8)));

__device__ __forceinline__ short f2bf(float f) {
    __hip_bfloat16 h = __float2bfloat16(f);
    return __builtin_bit_cast(short, h);
}
__device__ __forceinline__ float bf2f(short s) {
    return __bfloat162float(__builtin_bit_cast(__hip_bfloat16, s));
}

// ---------------- scatter-mean: fp32 source ----------------
__global__ __launch_bounds__(256) void scatter_f32(
    const float* __restrict__ xsrc, const int* __restrict__ src,
    const int* __restrict__ dst, float* __restrict__ agg,
    float* __restrict__ cnt, int nE) {
    int gid = blockIdx.x * 256 + threadIdx.x;
    int e = gid >> 6, lane = gid & 63;
    if (e >= nE) return;
    int s = src[e], d = dst[e];
    const float2* row = reinterpret_cast<const float2*>(xsrc + (size_t)s * D);
    float2 v = row[lane];
    float* out = agg + (size_t)d * D + lane * 2;
    unsafeAtomicAdd(out, v.x);
    unsafeAtomicAdd(out + 1, v.y);
    if (lane == 0) unsafeAtomicAdd(cnt + d, 1.0f);
}

// ---------------- scatter-mean: bf16 source ----------------
__global__ __launch_bounds__(256) void scatter_bf16(
    const short* __restrict__ xsrc, const int* __restrict__ src,
    const int* __restrict__ dst, float* __restrict__ agg,
    float* __restrict__ cnt, int nE) {
    int gid = blockIdx.x * 256 + threadIdx.x;
    int e = gid >> 6, lane = gid & 63;
    if (e >= nE) return;
    int s = src[e], d = dst[e];
    const ushort2* row = reinterpret_cast<const ushort2*>(xsrc + (size_t)s * D);
    ushort2 v = row[lane];
    float* out = agg + (size_t)d * D + lane * 2;
    unsafeAtomicAdd(out, bf2f((short)v.x));
    unsafeAtomicAdd(out + 1, bf2f((short)v.y));
    if (lane == 0) unsafeAtomicAdd(cnt + d, 1.0f);
}

// ---------------- fused node update ----------------
// out[n] = relu( mean[n] @ Wl + bl + x_tgt[n] @ Wr )
// as one GEMM: [mean | x_tgt] (K=256) @ vstack(Wl, Wr) (256x128)
// Weights staged in LDS as bf16, transposed [j][k], XOR-swizzled.
// A-fragments built straight from global memory (coalesced 128B/row per k-step).
template <bool XBF16, bool OUTBF16>
__global__ __launch_bounds__(256) void sage_update(
    const float* __restrict__ agg, const float* __restrict__ cnt,
    const void* __restrict__ xtgt_v, const float* __restrict__ Wl,
    const float* __restrict__ Wr, const float* __restrict__ bl,
    void* __restrict__ out_v, int ntiles) {
    __shared__ __align__(16) char wt[128 * 256 * 2];  // WT[j][kk] bf16, 64KB

    // ---- stage weights: WT[j][kk] = (kk<128 ? Wl[kk][j] : Wr[kk-128][j]) ----
    {
        int t = threadIdx.x;
        int j = t & 127;
        int half = t >> 7;  // 0 -> Wl, 1 -> Wr
        const float* W = half ? Wr : Wl;
        for (int k = 0; k < 128; ++k) {
            float v = W[k * 128 + j];  // coalesced over j
            int kk = half * 128 + k;
            int byte = (j * 512 + kk * 2) ^ ((j & 7) << 4);
            *reinterpret_cast<short*>(wt + byte) = f2bf(v);
        }
    }
    __syncthreads();

    const int wave = threadIdx.x >> 6, lane = threadIdx.x & 63;
    const int rl = lane & 15;   // A row / B col / D col (local)
    const int kq = lane >> 4;   // k-quarter

    float blv[8];
#pragma unroll
    for (int nt = 0; nt < 8; ++nt) blv[nt] = bl[nt * 16 + rl];

    for (int tile = blockIdx.x; tile < ntiles; tile += gridDim.x) {
        const int grow = tile * 64 + wave * 16 + rl;  // row this lane LOADS for A
        const float rc = 1.0f / fmaxf(cnt[grow], 1.0f);
        f32x4 acc[8] = {};

#pragma unroll
        for (int ks = 0; ks < 8; ++ks) {
            const int k0 = ks * 32 + kq * 8;  // k within concat-K [0,256)
            bf16x8 af;
            if (ks < 4) {
                // mean side: agg[grow][k0..k0+7] * rc
                const float4* p =
                    reinterpret_cast<const float4*>(agg + (size_t)grow * D + k0);
                float4 a = p[0], b = p[1];
                af[0] = f2bf(a.x * rc); af[1] = f2bf(a.y * rc);
                af[2] = f2bf(a.z * rc); af[3] = f2bf(a.w * rc);
                af[4] = f2bf(b.x * rc); af[5] = f2bf(b.y * rc);
                af[6] = f2bf(b.z * rc); af[7] = f2bf(b.w * rc);
            } else {
                const int kx = k0 - 128;
                if (XBF16) {
                    af = *reinterpret_cast<const bf16x8*>(
                        (const short*)xtgt_v + (size_t)grow * D + kx);
                } else {
                    const float4* p = reinterpret_cast<const float4*>(
                        (const float*)xtgt_v + (size_t)grow * D + kx);
                    float4 a = p[0], b = p[1];
                    af[0] = f2bf(a.x); af[1] = f2bf(a.y);
                    af[2] = f2bf(a.z); af[3] = f2bf(a.w);
                    af[4] = f2bf(b.x); af[5] = f2bf(b.y);
                    af[6] = f2bf(b.z); af[7] = f2bf(b.w);
                }
            }
#pragma unroll
            for (int nt = 0; nt < 8; ++nt) {
                const int j = nt * 16 + rl;
                const int byte = (j * 512 + k0 * 2) ^ ((j & 7) << 4);
                bf16x8 bfr = *reinterpret_cast<const bf16x8*>(wt + byte);
                acc[nt] =
                    __builtin_amdgcn_mfma_f32_16x16x32_bf16(af, bfr, acc[nt], 0, 0, 0);
            }
        }

        // epilogue: D layout col = lane&15 (+16*nt), row = (lane>>4)*4 + r
        const int orow_base = tile * 64 + wave * 16 + kq * 4;
#pragma unroll
        for (int nt = 0; nt < 8; ++nt) {
            const int col = nt * 16 + rl;
#pragma unroll
            for (int r = 0; r < 4; ++r) {
                float v = acc[nt][r] + blv[nt];
                v = fmaxf(v, 0.0f);
                const size_t idx = (size_t)(orow_base + r) * D + col;
                if (OUTBF16)
                    ((short*)out_v)[idx] = f2bf(v);
                else
                    ((float*)out_v)[idx] = v;
            }
        }
    }
}

extern "C" void kernel_launch(void* const* d_in, const int* in_sizes, int n_in,
                              void* d_out, int out_size, void* d_ws, size_t ws_size,
                              hipStream_t stream) {
    const float* x   = (const float*)d_in[0];
    const float* Wl0 = (const float*)d_in[1];
    const float* bl0 = (const float*)d_in[2];
    const float* Wr0 = (const float*)d_in[3];
    const float* Wl1 = (const float*)d_in[4];
    const float* bl1 = (const float*)d_in[5];
    const float* Wr1 = (const float*)d_in[6];
    const int* src0  = (const int*)d_in[7];
    const int* dst0  = (const int*)d_in[8];
    const int* src1  = (const int*)d_in[9];
    const int* dst1  = (const int*)d_in[10];

    char* ws = (char*)d_ws;
    // layout: agg0 64MB | cnt0 512KB | agg1 4MB | cnt1 32KB | h(bf16) 32MB
    float* agg0 = (float*)(ws);
    float* cnt0 = (float*)(ws + 67108864);
    float* agg1 = (float*)(ws + 67633152);
    float* cnt1 = (float*)(ws + 71827456);
    short* h    = (short*)(ws + 71860224);

    // zero the accumulators + counters (first 71,860,224 bytes)
    hipMemsetAsync(d_ws, 0, 71860224, stream);

    // layer 0
    scatter_f32<<<E0_ / 4, 256, 0, stream>>>(x, src0, dst0, agg0, cnt0, E0_);
    sage_update<false, true><<<512, 256, 0, stream>>>(
        agg0, cnt0, x, Wl0, Wr0, bl0, h, N1_ / 64);

    // layer 1
    scatter_bf16<<<E1_ / 4, 256, 0, stream>>>(h, src1, dst1, agg1, cnt1, E1_);
    sage_update<true, false><<<128, 256, 0, stream>>>(
        agg1, cnt1, h, Wl1, Wr1, bl1, d_out, N2_ / 64);
}

// Round 2
// 334.392 us; speedup vs baseline: 3.3199x; 3.3199x over previous
//
#include <hip/hip_runtime.h>
#include <hip/hip_bf16.h>

#define D 128
#define N0_ 1048576
#define N1_ 131072
#define N2_ 8192
#define E0_ 1048576
#define E1_ 131072

typedef float f32x4 __attribute__((ext_vector_type(4)));
typedef short bf16x8 __attribute__((ext_vector_type(8)));

__device__ __forceinline__ short f2bf(float f) {
    __hip_bfloat16 h = __float2bfloat16(f);
    return __builtin_bit_cast(short, h);
}
__device__ __forceinline__ float bf2f(short s) {
    return __bfloat162float(__builtin_bit_cast(__hip_bfloat16, s));
}

// ---------------- CSR build ----------------
__global__ __launch_bounds__(256) void hist_kernel(const int* __restrict__ dst,
                                                   int* __restrict__ deg, int nE) {
    int e = blockIdx.x * 256 + threadIdx.x;
    if (e < nE) atomicAdd(&deg[dst[e]], 1);
}

// phase 1: per-256-chunk exclusive scan + chunk totals
__global__ __launch_bounds__(256) void scan1(const int* __restrict__ deg,
                                             int* __restrict__ offs,
                                             int* __restrict__ bsum, int n) {
    __shared__ int ws[4];
    int i = blockIdx.x * 256 + threadIdx.x;
    int lane = threadIdx.x & 63, wid = threadIdx.x >> 6;
    int v = (i < n) ? deg[i] : 0;
    int incl = v;
#pragma unroll
    for (int d = 1; d < 64; d <<= 1) {
        int u = __shfl_up(incl, d);
        if (lane >= d) incl += u;
    }
    if (lane == 63) ws[wid] = incl;
    __syncthreads();
    if (threadIdx.x == 0) {
        int a = 0;
        for (int w = 0; w < 4; ++w) { int t = ws[w]; ws[w] = a; a += t; }
        bsum[blockIdx.x] = a;
    }
    __syncthreads();
    if (i < n) offs[i] = incl - v + ws[wid];
}

// phase 2: exclusive scan of chunk totals (single block, up to 512)
__global__ __launch_bounds__(512) void scan2(int* __restrict__ bsum, int nb) {
    __shared__ int ws[8];
    int i = threadIdx.x, lane = i & 63, wid = i >> 6;
    int v = (i < nb) ? bsum[i] : 0;
    int incl = v;
#pragma unroll
    for (int d = 1; d < 64; d <<= 1) {
        int u = __shfl_up(incl, d);
        if (lane >= d) incl += u;
    }
    if (lane == 63) ws[wid] = incl;
    __syncthreads();
    if (i == 0) {
        int a = 0;
        for (int w = 0; w < 8; ++w) { int t = ws[w]; ws[w] = a; a += t; }
    }
    __syncthreads();
    if (i < nb) bsum[i] = incl - v + ws[wid];
}

// phase 3: add chunk offsets; init cursor copy
__global__ __launch_bounds__(256) void scan3(int* __restrict__ offs,
                                             const int* __restrict__ bsum,
                                             int* __restrict__ cur, int n) {
    int i = blockIdx.x * 256 + threadIdx.x;
    if (i < n) {
        int o = offs[i] + bsum[blockIdx.x];
        offs[i] = o;
        cur[i] = o;
    }
}

__global__ __launch_bounds__(256) void scatter_edges(const int* __restrict__ src,
                                                     const int* __restrict__ dst,
                                                     int* __restrict__ cur,
                                                     int* __restrict__ eidx, int nE) {
    int e = blockIdx.x * 256 + threadIdx.x;
    if (e < nE) {
        int pos = atomicAdd(&cur[dst[e]], 1);
        eidx[pos] = src[e];
    }
}

// ---------------- aggregate: one wave per target, no atomics ----------------
template <bool SRCBF16>
__global__ __launch_bounds__(256) void aggregate(const void* __restrict__ xsrc_v,
                                                 const int* __restrict__ eidx,
                                                 const int* __restrict__ offs,
                                                 const int* __restrict__ deg,
                                                 short* __restrict__ mean, int ntgt) {
    const int lane = threadIdx.x & 63;
    const int gw = (blockIdx.x * 256 + threadIdx.x) >> 6;
    const int nw = (gridDim.x * 256) >> 6;
    for (int t = gw; t < ntgt; t += nw) {
        const int start = offs[t], d = deg[t];
        float ax = 0.0f, ay = 0.0f;
        for (int base = 0; base < d; base += 64) {
            const int nc = min(64, d - base);
            int sidx = (lane < nc) ? eidx[start + base + lane] : 0;
            int i = 0;
            for (; i + 1 < nc; i += 2) {
                int s0 = __shfl(sidx, i), s1 = __shfl(sidx, i + 1);
                if (SRCBF16) {
                    const short* xs = (const short*)xsrc_v;
                    ushort2 v0 = ((const ushort2*)(xs + (size_t)s0 * D))[lane];
                    ushort2 v1 = ((const ushort2*)(xs + (size_t)s1 * D))[lane];
                    ax += bf2f((short)v0.x) + bf2f((short)v1.x);
                    ay += bf2f((short)v0.y) + bf2f((short)v1.y);
                } else {
                    const float* xs = (const float*)xsrc_v;
                    float2 v0 = ((const float2*)(xs + (size_t)s0 * D))[lane];
                    float2 v1 = ((const float2*)(xs + (size_t)s1 * D))[lane];
                    ax += v0.x + v1.x;
                    ay += v0.y + v1.y;
                }
            }
            if (i < nc) {
                int s0 = __shfl(sidx, i);
                if (SRCBF16) {
                    const short* xs = (const short*)xsrc_v;
                    ushort2 v0 = ((const ushort2*)(xs + (size_t)s0 * D))[lane];
                    ax += bf2f((short)v0.x);
                    ay += bf2f((short)v0.y);
                } else {
                    const float* xs = (const float*)xsrc_v;
                    float2 v0 = ((const float2*)(xs + (size_t)s0 * D))[lane];
                    ax += v0.x;
                    ay += v0.y;
                }
            }
        }
        const float r = (d > 0) ? 1.0f / (float)d : 0.0f;
        ushort2 o;
        o.x = (unsigned short)f2bf(ax * r);
        o.y = (unsigned short)f2bf(ay * r);
        ((ushort2*)(mean + (size_t)t * D))[lane] = o;
    }
}

// ---------------- fused node update ----------------
// out[n] = relu( [mean(bf16) | x_tgt] @ vstack(Wl,Wr) + bl )
template <bool XBF16, bool OUTBF16>
__global__ __launch_bounds__(256) void sage_update(
    const short* __restrict__ mean, const void* __restrict__ xtgt_v,
    const float* __restrict__ Wl, const float* __restrict__ Wr,
    const float* __restrict__ bl, void* __restrict__ out_v, int ntiles) {
    __shared__ __align__(16) char wt[128 * 256 * 2];  // WT[j][kk] bf16, 64KB

    {
        int t = threadIdx.x;
        int j = t & 127;
        int half = t >> 7;  // 0 -> Wl, 1 -> Wr
        const float* W = half ? Wr : Wl;
        for (int k = 0; k < 128; ++k) {
            float v = W[k * 128 + j];  // coalesced over j
            int kk = half * 128 + k;
            int byte = (j * 512 + kk * 2) ^ ((j & 7) << 4);
            *reinterpret_cast<short*>(wt + byte) = f2bf(v);
        }
    }
    __syncthreads();

    const int wave = threadIdx.x >> 6, lane = threadIdx.x & 63;
    const int rl = lane & 15;
    const int kq = lane >> 4;

    float blv[8];
#pragma unroll
    for (int nt = 0; nt < 8; ++nt) blv[nt] = bl[nt * 16 + rl];

    for (int tile = blockIdx.x; tile < ntiles; tile += gridDim.x) {
        const int grow = tile * 64 + wave * 16 + rl;
        f32x4 acc[8] = {};

#pragma unroll
        for (int ks = 0; ks < 8; ++ks) {
            const int k0 = ks * 32 + kq * 8;
            bf16x8 af;
            if (ks < 4) {
                af = *reinterpret_cast<const bf16x8*>(mean + (size_t)grow * D + k0);
            } else {
                const int kx = k0 - 128;
                if (XBF16) {
                    af = *reinterpret_cast<const bf16x8*>(
                        (const short*)xtgt_v + (size_t)grow * D + kx);
                } else {
                    const float4* p = reinterpret_cast<const float4*>(
                        (const float*)xtgt_v + (size_t)grow * D + kx);
                    float4 a = p[0], b = p[1];
                    af[0] = f2bf(a.x); af[1] = f2bf(a.y);
                    af[2] = f2bf(a.z); af[3] = f2bf(a.w);
                    af[4] = f2bf(b.x); af[5] = f2bf(b.y);
                    af[6] = f2bf(b.z); af[7] = f2bf(b.w);
                }
            }
#pragma unroll
            for (int nt = 0; nt < 8; ++nt) {
                const int j = nt * 16 + rl;
                const int byte = (j * 512 + k0 * 2) ^ ((j & 7) << 4);
                bf16x8 bfr = *reinterpret_cast<const bf16x8*>(wt + byte);
                acc[nt] =
                    __builtin_amdgcn_mfma_f32_16x16x32_bf16(af, bfr, acc[nt], 0, 0, 0);
            }
        }

        const int orow_base = tile * 64 + wave * 16 + kq * 4;
#pragma unroll
        for (int nt = 0; nt < 8; ++nt) {
            const int col = nt * 16 + rl;
#pragma unroll
            for (int r = 0; r < 4; ++r) {
                float v = acc[nt][r] + blv[nt];
                v = fmaxf(v, 0.0f);
                const size_t idx = (size_t)(orow_base + r) * D + col;
                if (OUTBF16)
                    ((short*)out_v)[idx] = f2bf(v);
                else
                    ((float*)out_v)[idx] = v;
            }
        }
    }
}

extern "C" void kernel_launch(void* const* d_in, const int* in_sizes, int n_in,
                              void* d_out, int out_size, void* d_ws, size_t ws_size,
                              hipStream_t stream) {
    const float* x   = (const float*)d_in[0];
    const float* Wl0 = (const float*)d_in[1];
    const float* bl0 = (const float*)d_in[2];
    const float* Wr0 = (const float*)d_in[3];
    const float* Wl1 = (const float*)d_in[4];
    const float* bl1 = (const float*)d_in[5];
    const float* Wr1 = (const float*)d_in[6];
    const int* src0  = (const int*)d_in[7];
    const int* dst0  = (const int*)d_in[8];
    const int* src1  = (const int*)d_in[9];
    const int* dst1  = (const int*)d_in[10];

    char* ws = (char*)d_ws;
    // layout (bytes):
    int*   deg0  = (int*)(ws);                       // 524288
    int*   deg1  = (int*)(ws + 524288);              // 32768
    int*   cur0  = (int*)(ws + 557056);              // 524288
    int*   cur1  = (int*)(ws + 1081344);             // 32768
    int*   bsum  = (int*)(ws + 1114112);             // 4096
    int*   offs0 = (int*)(ws + 1118208);             // 524288
    int*   offs1 = (int*)(ws + 1642496);             // 32768
    int*   eidx0 = (int*)(ws + 1675264);             // 4194304
    int*   eidx1 = (int*)(ws + 5869568);             // 524288
    short* mean0 = (short*)(ws + 6393856);           // 33554432
    short* mean1 = (short*)(ws + 39948288);          // 2097152
    short* h     = (short*)(ws + 42045440);          // 33554432

    // zero only the degree histograms (deg0 | deg1 contiguous)
    hipMemsetAsync(ws, 0, 557056, stream);

    // ---- layer 0 CSR + aggregate ----
    hist_kernel<<<E0_ / 256, 256, 0, stream>>>(dst0, deg0, E0_);
    scan1<<<N1_ / 256, 256, 0, stream>>>(deg0, offs0, bsum, N1_);
    scan2<<<1, 512, 0, stream>>>(bsum, N1_ / 256);
    scan3<<<N1_ / 256, 256, 0, stream>>>(offs0, bsum, cur0, N1_);
    scatter_edges<<<E0_ / 256, 256, 0, stream>>>(src0, dst0, cur0, eidx0, E0_);
    aggregate<false><<<4096, 256, 0, stream>>>(x, eidx0, offs0, deg0, mean0, N1_);
    sage_update<false, true><<<1024, 256, 0, stream>>>(
        mean0, x, Wl0, Wr0, bl0, h, N1_ / 64);

    // ---- layer 1 CSR + aggregate ----
    hist_kernel<<<E1_ / 256, 256, 0, stream>>>(dst1, deg1, E1_);
    scan1<<<N2_ / 256, 256, 0, stream>>>(deg1, offs1, bsum, N2_);
    scan2<<<1, 512, 0, stream>>>(bsum, N2_ / 256);
    scan3<<<N2_ / 256, 256, 0, stream>>>(offs1, bsum, cur1, N2_);
    scatter_edges<<<E1_ / 256, 256, 0, stream>>>(src1, dst1, cur1, eidx1, E1_);
    aggregate<true><<<2048, 256, 0, stream>>>(h, eidx1, offs1, deg1, mean1, N2_);
    sage_update<true, false><<<128, 256, 0, stream>>>(
        mean1, h, Wl1, Wr1, bl1, d_out, N2_ / 64);
}

// Round 3
// 324.065 us; speedup vs baseline: 3.4257x; 1.0319x over previous
//
#include <hip/hip_runtime.h>
#include <hip/hip_bf16.h>

#define D 128
#define N0_ 1048576
#define N1_ 131072
#define N2_ 8192
#define E0_ 1048576
#define E1_ 131072

typedef float f32x4 __attribute__((ext_vector_type(4)));
typedef short bf16x8 __attribute__((ext_vector_type(8)));

__device__ __forceinline__ short f2bf(float f) {
    __hip_bfloat16 h = __float2bfloat16(f);
    return __builtin_bit_cast(short, h);
}
__device__ __forceinline__ float bf2f(short s) {
    return __bfloat162float(__builtin_bit_cast(__hip_bfloat16, s));
}

// ---------------- zero scratch (replaces hipMemsetAsync fill node) ----------------
__global__ __launch_bounds__(256) void zero_kernel(int4* __restrict__ p, int n4) {
    int i = blockIdx.x * 256 + threadIdx.x;
    if (i < n4) p[i] = int4{0, 0, 0, 0};
}

// ---------------- CSR build ----------------
__global__ __launch_bounds__(256) void hist_kernel(const int* __restrict__ dst,
                                                   int* __restrict__ deg, int nE) {
    int e = blockIdx.x * 256 + threadIdx.x;
    if (e < nE) atomicAdd(&deg[dst[e]], 1);
}

__global__ __launch_bounds__(256) void scan1(const int* __restrict__ deg,
                                             int* __restrict__ offs,
                                             int* __restrict__ bsum, int n) {
    __shared__ int ws[4];
    int i = blockIdx.x * 256 + threadIdx.x;
    int lane = threadIdx.x & 63, wid = threadIdx.x >> 6;
    int v = (i < n) ? deg[i] : 0;
    int incl = v;
#pragma unroll
    for (int d = 1; d < 64; d <<= 1) {
        int u = __shfl_up(incl, d);
        if (lane >= d) incl += u;
    }
    if (lane == 63) ws[wid] = incl;
    __syncthreads();
    if (threadIdx.x == 0) {
        int a = 0;
        for (int w = 0; w < 4; ++w) { int t = ws[w]; ws[w] = a; a += t; }
        bsum[blockIdx.x] = a;
    }
    __syncthreads();
    if (i < n) offs[i] = incl - v + ws[wid];
}

__global__ __launch_bounds__(512) void scan2(int* __restrict__ bsum, int nb) {
    __shared__ int ws[8];
    int i = threadIdx.x, lane = i & 63, wid = i >> 6;
    int v = (i < nb) ? bsum[i] : 0;
    int incl = v;
#pragma unroll
    for (int d = 1; d < 64; d <<= 1) {
        int u = __shfl_up(incl, d);
        if (lane >= d) incl += u;
    }
    if (lane == 63) ws[wid] = incl;
    __syncthreads();
    if (i == 0) {
        int a = 0;
        for (int w = 0; w < 8; ++w) { int t = ws[w]; ws[w] = a; a += t; }
    }
    __syncthreads();
    if (i < nb) bsum[i] = incl - v + ws[wid];
}

__global__ __launch_bounds__(256) void scan3(int* __restrict__ offs,
                                             const int* __restrict__ bsum,
                                             int* __restrict__ cur, int n) {
    int i = blockIdx.x * 256 + threadIdx.x;
    if (i < n) {
        int o = offs[i] + bsum[blockIdx.x];
        offs[i] = o;
        cur[i] = o;
    }
}

__global__ __launch_bounds__(256) void scatter_edges(const int* __restrict__ src,
                                                     const int* __restrict__ dst,
                                                     int* __restrict__ cur,
                                                     int* __restrict__ eidx, int nE) {
    int e = blockIdx.x * 256 + threadIdx.x;
    if (e < nE) {
        int pos = atomicAdd(&cur[dst[e]], 1);
        eidx[pos] = src[e];
    }
}

// ---------------- aggregate: one wave per target, 8 gathers in flight ----------------
template <bool SRCBF16>
__device__ __forceinline__ float2 row_load(const void* xsrc_v, int s, int lane) {
    if (SRCBF16) {
        const short* xs = (const short*)xsrc_v;
        ushort2 v = ((const ushort2*)(xs + (size_t)s * D))[lane];
        return float2{bf2f((short)v.x), bf2f((short)v.y)};
    } else {
        const float* xs = (const float*)xsrc_v;
        return ((const float2*)(xs + (size_t)s * D))[lane];
    }
}

template <bool SRCBF16>
__global__ __launch_bounds__(256) void aggregate(const void* __restrict__ xsrc_v,
                                                 const int* __restrict__ eidx,
                                                 const int* __restrict__ offs,
                                                 const int* __restrict__ deg,
                                                 short* __restrict__ mean, int ntgt) {
    const int lane = threadIdx.x & 63;
    const int gw = (blockIdx.x * 256 + threadIdx.x) >> 6;
    const int nw = (gridDim.x * 256) >> 6;
    for (int t = gw; t < ntgt; t += nw) {
        const int start = offs[t], d = deg[t];
        float ax = 0.0f, ay = 0.0f;
        for (int base = 0; base < d; base += 64) {
            const int nc = min(64, d - base);
            int sidx = (lane < nc) ? eidx[start + base + lane] : 0;
            int i = 0;
            for (; i + 8 <= nc; i += 8) {
                float2 v[8];
#pragma unroll
                for (int u = 0; u < 8; ++u) {
                    int s = __shfl(sidx, i + u);
                    v[u] = row_load<SRCBF16>(xsrc_v, s, lane);
                }
#pragma unroll
                for (int u = 0; u < 8; ++u) { ax += v[u].x; ay += v[u].y; }
            }
            for (; i + 4 <= nc; i += 4) {
                float2 v[4];
#pragma unroll
                for (int u = 0; u < 4; ++u) {
                    int s = __shfl(sidx, i + u);
                    v[u] = row_load<SRCBF16>(xsrc_v, s, lane);
                }
#pragma unroll
                for (int u = 0; u < 4; ++u) { ax += v[u].x; ay += v[u].y; }
            }
            for (; i < nc; ++i) {
                int s = __shfl(sidx, i);
                float2 v = row_load<SRCBF16>(xsrc_v, s, lane);
                ax += v.x;
                ay += v.y;
            }
        }
        const float r = (d > 0) ? 1.0f / (float)d : 0.0f;
        ushort2 o;
        o.x = (unsigned short)f2bf(ax * r);
        o.y = (unsigned short)f2bf(ay * r);
        ((ushort2*)(mean + (size_t)t * D))[lane] = o;
    }
}

// ---------------- fused node update ----------------
// out[n] = relu( [mean(bf16) | x_tgt] @ vstack(Wl,Wr) + bl )
template <bool XBF16, bool OUTBF16>
__global__ __launch_bounds__(256) void sage_update(
    const short* __restrict__ mean, const void* __restrict__ xtgt_v,
    const float* __restrict__ Wl, const float* __restrict__ Wr,
    const float* __restrict__ bl, void* __restrict__ out_v, int ntiles) {
    __shared__ __align__(16) char wt[128 * 256 * 2];  // WT[j][kk] bf16, 64KB

    {
        int t = threadIdx.x;
        int j = t & 127;
        int half = t >> 7;  // 0 -> Wl, 1 -> Wr
        const float* W = half ? Wr : Wl;
        for (int k = 0; k < 128; ++k) {
            float v = W[k * 128 + j];  // coalesced over j
            int kk = half * 128 + k;
            int byte = (j * 512 + kk * 2) ^ ((j & 7) << 4);
            *reinterpret_cast<short*>(wt + byte) = f2bf(v);
        }
    }
    __syncthreads();

    const int wave = threadIdx.x >> 6, lane = threadIdx.x & 63;
    const int rl = lane & 15;
    const int kq = lane >> 4;

    float blv[8];
#pragma unroll
    for (int nt = 0; nt < 8; ++nt) blv[nt] = bl[nt * 16 + rl];

    for (int tile = blockIdx.x; tile < ntiles; tile += gridDim.x) {
        const int grow = tile * 64 + wave * 16 + rl;
        f32x4 acc[8] = {};

#pragma unroll
        for (int ks = 0; ks < 8; ++ks) {
            const int k0 = ks * 32 + kq * 8;
            bf16x8 af;
            if (ks < 4) {
                af = *reinterpret_cast<const bf16x8*>(mean + (size_t)grow * D + k0);
            } else {
                const int kx = k0 - 128;
                if (XBF16) {
                    af = *reinterpret_cast<const bf16x8*>(
                        (const short*)xtgt_v + (size_t)grow * D + kx);
                } else {
                    const float4* p = reinterpret_cast<const float4*>(
                        (const float*)xtgt_v + (size_t)grow * D + kx);
                    float4 a = p[0], b = p[1];
                    af[0] = f2bf(a.x); af[1] = f2bf(a.y);
                    af[2] = f2bf(a.z); af[3] = f2bf(a.w);
                    af[4] = f2bf(b.x); af[5] = f2bf(b.y);
                    af[6] = f2bf(b.z); af[7] = f2bf(b.w);
                }
            }
#pragma unroll
            for (int nt = 0; nt < 8; ++nt) {
                const int j = nt * 16 + rl;
                const int byte = (j * 512 + k0 * 2) ^ ((j & 7) << 4);
                bf16x8 bfr = *reinterpret_cast<const bf16x8*>(wt + byte);
                acc[nt] =
                    __builtin_amdgcn_mfma_f32_16x16x32_bf16(af, bfr, acc[nt], 0, 0, 0);
            }
        }

        const int orow_base = tile * 64 + wave * 16 + kq * 4;
#pragma unroll
        for (int nt = 0; nt < 8; ++nt) {
            const int col = nt * 16 + rl;
#pragma unroll
            for (int r = 0; r < 4; ++r) {
                float v = acc[nt][r] + blv[nt];
                v = fmaxf(v, 0.0f);
                const size_t idx = (size_t)(orow_base + r) * D + col;
                if (OUTBF16)
                    ((short*)out_v)[idx] = f2bf(v);
                else
                    ((float*)out_v)[idx] = v;
            }
        }
    }
}

extern "C" void kernel_launch(void* const* d_in, const int* in_sizes, int n_in,
                              void* d_out, int out_size, void* d_ws, size_t ws_size,
                              hipStream_t stream) {
    const float* x   = (const float*)d_in[0];
    const float* Wl0 = (const float*)d_in[1];
    const float* bl0 = (const float*)d_in[2];
    const float* Wr0 = (const float*)d_in[3];
    const float* Wl1 = (const float*)d_in[4];
    const float* bl1 = (const float*)d_in[5];
    const float* Wr1 = (const float*)d_in[6];
    const int* src0  = (const int*)d_in[7];
    const int* dst0  = (const int*)d_in[8];
    const int* src1  = (const int*)d_in[9];
    const int* dst1  = (const int*)d_in[10];

    char* ws = (char*)d_ws;
    int*   deg0  = (int*)(ws);                       // 524288
    int*   deg1  = (int*)(ws + 524288);              // 32768
    int*   cur0  = (int*)(ws + 557056);              // 524288
    int*   cur1  = (int*)(ws + 1081344);             // 32768
    int*   bsum  = (int*)(ws + 1114112);             // 4096
    int*   offs0 = (int*)(ws + 1118208);             // 524288
    int*   offs1 = (int*)(ws + 1642496);             // 32768
    int*   eidx0 = (int*)(ws + 1675264);             // 4194304
    int*   eidx1 = (int*)(ws + 5869568);             // 524288
    short* mean0 = (short*)(ws + 6393856);           // 33554432
    short* mean1 = (short*)(ws + 39948288);          // 2097152
    short* h     = (short*)(ws + 42045440);          // 33554432

    // zero deg0|deg1 (557056 bytes = 34816 int4)
    zero_kernel<<<136, 256, 0, stream>>>((int4*)ws, 34816);

    // ---- layer 0 CSR + aggregate ----
    hist_kernel<<<E0_ / 256, 256, 0, stream>>>(dst0, deg0, E0_);
    scan1<<<N1_ / 256, 256, 0, stream>>>(deg0, offs0, bsum, N1_);
    scan2<<<1, 512, 0, stream>>>(bsum, N1_ / 256);
    scan3<<<N1_ / 256, 256, 0, stream>>>(offs0, bsum, cur0, N1_);
    scatter_edges<<<E0_ / 256, 256, 0, stream>>>(src0, dst0, cur0, eidx0, E0_);
    aggregate<false><<<4096, 256, 0, stream>>>(x, eidx0, offs0, deg0, mean0, N1_);
    sage_update<false, true><<<1024, 256, 0, stream>>>(
        mean0, x, Wl0, Wr0, bl0, h, N1_ / 64);

    // ---- layer 1 CSR + aggregate ----
    hist_kernel<<<E1_ / 256, 256, 0, stream>>>(dst1, deg1, E1_);
    scan1<<<N2_ / 256, 256, 0, stream>>>(deg1, offs1, bsum, N2_);
    scan2<<<1, 512, 0, stream>>>(bsum, N2_ / 256);
    scan3<<<N2_ / 256, 256, 0, stream>>>(offs1, bsum, cur1, N2_);
    scatter_edges<<<E1_ / 256, 256, 0, stream>>>(src1, dst1, cur1, eidx1, E1_);
    aggregate<true><<<2048, 256, 0, stream>>>(h, eidx1, offs1, deg1, mean1, N2_);
    sage_update<true, false><<<128, 256, 0, stream>>>(
        mean1, h, Wl1, Wr1, bl1, d_out, N2_ / 64);
}